// Round 25
// baseline (106.865 us; speedup 1.0000x reference)
//
#include <hip/hip_runtime.h>
#include <math.h>

constexpr int Dm  = 1024;
constexpr int NH  = 16;
constexpr int SQ  = 2048;
constexpr int NB  = 2;

typedef float f32x4 __attribute__((ext_vector_type(4)));
typedef float f32x16 __attribute__((ext_vector_type(16)));
typedef short bf16x8 __attribute__((ext_vector_type(8)));
typedef __attribute__((address_space(3))) unsigned int lds_u32;
typedef __attribute__((address_space(1))) const unsigned int glb_u32;

__device__ __forceinline__ void gload_lds16(const void* g, void* l) {
    __builtin_amdgcn_global_load_lds((glb_u32*)(uintptr_t)g, (lds_u32*)(uintptr_t)l, 16, 0, 0);
}

__device__ __forceinline__ unsigned short bf_round(float x) {
    unsigned u = __float_as_uint(x);
    unsigned r = u + 0x7fffu + ((u >> 16) & 1u);
    return (unsigned short)(r >> 16);
}

__device__ __forceinline__ float exp2_fast(float x) {
    float r;
    asm("v_exp_f32 %0, %1" : "=v"(r) : "v"(x));
    return r;
}

__device__ __forceinline__ unsigned cvt_pk(float lo, float hi_) {
    unsigned r;
    asm("v_cvt_pk_bf16_f32 %0, %1, %2" : "=v"(r) : "v"(lo), "v"(hi_));
    return r;
}

__device__ __forceinline__ void permlane_swap(unsigned& a, unsigned& b) {
    asm volatile("v_permlane32_swap_b32 %0, %1" : "+v"(a), "+v"(b));
}

__device__ __forceinline__ bf16x8 make_frag(unsigned a, unsigned b, unsigned c, unsigned d) {
    union { unsigned u[4]; bf16x8 v; } uu;
    uu.u[0] = a; uu.u[1] = b; uu.u[2] = c; uu.u[3] = d;
    return uu.v;
}

// ---------------- prologue: W transpose (z=0..3) + x fp32->bf16 (z=4) ----------------
__global__ __launch_bounds__(256) void prologue(const float* __restrict__ x,
                                                const float* __restrict__ Wq,
                                                const float* __restrict__ Wk,
                                                const float* __restrict__ Wv,
                                                const float* __restrict__ Wo,
                                                unsigned short* __restrict__ xb,
                                                unsigned short* __restrict__ wt) {
    const int z = blockIdx.z;
    const int tid = threadIdx.x;
    if (z == 4) {
        size_t base = ((size_t)blockIdx.y * 16 + blockIdx.x) * 16384;
#pragma unroll
        for (int it = 0; it < 8; ++it) {
            size_t i = base + (size_t)it * 2048 + (size_t)tid * 8;
            float4 a = *(const float4*)&x[i];
            float4 b = *(const float4*)&x[i + 4];
            unsigned short o8[8] __attribute__((aligned(16)));
            o8[0] = bf_round(a.x); o8[1] = bf_round(a.y); o8[2] = bf_round(a.z); o8[3] = bf_round(a.w);
            o8[4] = bf_round(b.x); o8[5] = bf_round(b.y); o8[6] = bf_round(b.z); o8[7] = bf_round(b.w);
            *(uint4*)&xb[i] = *(const uint4*)o8;
        }
        return;
    }
    const float* W = (z == 0) ? Wq : (z == 1) ? Wk : (z == 2) ? Wv : Wo;
    unsigned short* dst = wt + (size_t)z * Dm * Dm;
    __shared__ float T[64][65];
    const int k0 = blockIdx.x * 64, n0 = blockIdx.y * 64;
#pragma unroll
    for (int i = 0; i < 4; ++i) {
        int s = tid + i * 256;
        int kk = s >> 4, c = (s & 15) * 4;
        *(float4*)&T[kk][c] = *(const float4*)&W[(size_t)(k0 + kk) * Dm + n0 + c];
    }
    __syncthreads();
#pragma unroll
    for (int i = 0; i < 2; ++i) {
        int s = tid + i * 256;
        int n = s >> 3, c8 = (s & 7) * 8;
        unsigned short o8[8] __attribute__((aligned(16)));
#pragma unroll
        for (int j = 0; j < 8; ++j) o8[j] = bf_round(T[c8 + j][n]);
        *(uint4*)&dst[(size_t)(n0 + n) * Dm + k0 + c8] = *(const uint4*)o8;
    }
}

// ====================================================================
// single-phase 256x192 QKV GEMM, ONE barrier per K-tile (round-20/21 verified)
// ====================================================================
__global__ __launch_bounds__(512) void gemm_qkv192(
    const unsigned short* __restrict__ xb,
    const unsigned short* __restrict__ wt,
    const float* __restrict__ bq, const float* __restrict__ bk,
    const float* __restrict__ bv,
    unsigned short* __restrict__ qbuf, unsigned short* __restrict__ kbuf,
    unsigned short* __restrict__ vtbuf)
{
    __shared__ unsigned short Alds[2][256 * 64];
    __shared__ unsigned short Blds[2][192 * 64];

    const int tid = threadIdx.x;
    const int lane = tid & 63, wid = tid >> 6;
    const int wm = wid >> 2, wn = wid & 3;
    const int l15 = lane & 15, lg = lane >> 4;

    const int bid = blockIdx.x;
    const int swz = (bid & 7) * 32 + (bid >> 3);
    const int bx = swz & 15, by = swz >> 4;
    const int m0 = by * 256, n0 = bx * 192;

    const int srow = wid * 8 + (lane >> 3);
    const int scol = ((lane & 7) ^ ((lane >> 3) & 7)) * 8;

    const unsigned short* Abase = xb + (size_t)m0 * Dm;
    const unsigned short* Bbase = wt + (size_t)n0 * Dm;

#define STAGE_TILE(t)                                                              \
    do {                                                                           \
        const unsigned short* As_ = Abase + (t) * 64;                              \
        const unsigned short* Bs_ = Bbase + (t) * 64;                              \
        unsigned short* Ad_ = Alds[(t) & 1];                                       \
        unsigned short* Bd_ = Blds[(t) & 1];                                       \
        _Pragma("unroll")                                                          \
        for (int i_ = 0; i_ < 4; ++i_)                                             \
            gload_lds16(&As_[(size_t)(i_ * 64 + srow) * Dm + scol],                \
                        &Ad_[i_ * 4096 + wid * 512]);                              \
        _Pragma("unroll")                                                          \
        for (int i_ = 0; i_ < 3; ++i_)                                             \
            gload_lds16(&Bs_[(size_t)(i_ * 64 + srow) * Dm + scol],                \
                        &Bd_[i_ * 4096 + wid * 512]);                              \
    } while (0)

    f32x4 acc[8][3];
#pragma unroll
    for (int mr = 0; mr < 8; ++mr)
#pragma unroll
        for (int nr = 0; nr < 3; ++nr) acc[mr][nr] = (f32x4){0.f, 0.f, 0.f, 0.f};

    STAGE_TILE(0);
    asm volatile("s_waitcnt vmcnt(0)" ::: "memory");
    __builtin_amdgcn_s_barrier();

    for (int t = 0; t < Dm / 64; ++t) {
        unsigned short* Ad = Alds[t & 1];
        unsigned short* Bd = Blds[t & 1];
        if (t + 1 < Dm / 64) STAGE_TILE(t + 1);

        bf16x8 a_[8][2], b_[3][2];

#define RD_A(qm, fr, ks) \
    (*(const bf16x8*)&Ad[(wm * 128 + (qm) * 64 + (fr) * 16 + l15) * 64 + \
                         ((((ks) * 4 + lg) ^ (l15 & 7)) * 8)])
#define RD_B(fc, ks) \
    (*(const bf16x8*)&Bd[(wn * 48 + (fc) * 16 + l15) * 64 + \
                         ((((ks) * 4 + lg) ^ (l15 & 7)) * 8)])

#pragma unroll
        for (int fr = 0; fr < 4; ++fr) {
            a_[fr][0] = RD_A(0, fr, 0);     a_[fr][1] = RD_A(0, fr, 1);
            a_[4 + fr][0] = RD_A(1, fr, 0); a_[4 + fr][1] = RD_A(1, fr, 1);
        }
#pragma unroll
        for (int fc = 0; fc < 3; ++fc) {
            b_[fc][0] = RD_B(fc, 0); b_[fc][1] = RD_B(fc, 1);
        }
        __builtin_amdgcn_s_setprio(1);
#pragma unroll
        for (int mr = 0; mr < 8; ++mr)
#pragma unroll
            for (int fc = 0; fc < 3; ++fc)
#pragma unroll
                for (int ks = 0; ks < 2; ++ks)
                    acc[mr][fc] = __builtin_amdgcn_mfma_f32_16x16x32_bf16(
                        a_[mr][ks], b_[fc][ks], acc[mr][fc], 0, 0, 0);
        __builtin_amdgcn_s_setprio(0);

        asm volatile("s_waitcnt vmcnt(0)" ::: "memory");
        __builtin_amdgcn_s_barrier();        // single barrier per K-tile
#undef RD_A
#undef RD_B
    }

    const float qscale = 0.18033688011f;   // 1/8 * log2(e)
#pragma unroll
    for (int mr = 0; mr < 8; ++mr) {
#pragma unroll
        for (int nr = 0; nr < 3; ++nr) {
            const int m = m0 + wm * 128 + mr * 16 + lg * 4;
            const int nglob = n0 + wn * 48 + nr * 16 + l15;
            const int zq = nglob >> 10;
            const int nz = nglob & 1023;
            const float* bias = (zq == 0) ? bq : (zq == 1) ? bk : bv;
            const float bb_ = bias[nz];
            if (zq == 0) {
#pragma unroll
                for (int rr = 0; rr < 4; ++rr)
                    qbuf[(size_t)(m + rr) * Dm + nz] =
                        bf_round((acc[mr][nr][rr] + bb_) * qscale);
            } else if (zq == 1) {
#pragma unroll
                for (int rr = 0; rr < 4; ++rr)
                    kbuf[(size_t)(m + rr) * Dm + nz] = bf_round(acc[mr][nr][rr] + bb_);
            } else {
                const int bbv = m >> 11, s = m & (SQ - 1);
                const int hh = nz >> 6, d = nz & 63;
                unsigned short p4[4] __attribute__((aligned(8)));
#pragma unroll
                for (int rr = 0; rr < 4; ++rr) p4[rr] = bf_round(acc[mr][nr][rr] + bb_);
                *(uint2*)&vtbuf[(((size_t)bbv * NH + hh) * 64 + d) * SQ + s] =
                    *(const uint2*)p4;
            }
        }
    }
#undef STAGE_TILE
}

// ====================================================================
// output projection, single-phase 128x128, ONE barrier per K-tile (round-20)
// ====================================================================
__global__ __launch_bounds__(256) void gemm_out8(const unsigned short* __restrict__ A,
                                                 const unsigned short* __restrict__ Bt,
                                                 const float* __restrict__ bias,
                                                 float* __restrict__ Cf) {
    __shared__ unsigned short Alds[2][128 * 64];
    __shared__ unsigned short Blds[2][128 * 64];

    const int tid = threadIdx.x;
    const int lane = tid & 63, wid = tid >> 6;
    const int l15 = lane & 15, lg = lane >> 4;
    const int wr = (wid >> 1) * 64, wc = (wid & 1) * 64;
    const int m0 = blockIdx.y * 128, n0 = blockIdx.x * 128;

    const int srow = (tid >> 3) & 31;
    const int scol = ((tid & 7) ^ (srow & 7)) * 8;

    const unsigned short* Abase = A + (size_t)m0 * Dm;
    const unsigned short* Bbase = Bt + (size_t)n0 * Dm;

#define STAGE_TILE(t)                                                              \
    do {                                                                           \
        const unsigned short* As_ = Abase + (t) * 64;                              \
        const unsigned short* Bs_ = Bbase + (t) * 64;                              \
        unsigned short* Ad_ = Alds[(t) & 1];                                       \
        unsigned short* Bd_ = Blds[(t) & 1];                                       \
        _Pragma("unroll")                                                          \
        for (int i_ = 0; i_ < 4; ++i_) {                                           \
            gload_lds16(&As_[(size_t)(i_ * 32 + srow) * Dm + scol],                \
                        &Ad_[i_ * 2048 + wid * 512]);                              \
            gload_lds16(&Bs_[(size_t)(i_ * 32 + srow) * Dm + scol],                \
                        &Bd_[i_ * 2048 + wid * 512]);                              \
        }                                                                          \
    } while (0)

    f32x4 acc[4][4];
#pragma unroll
    for (int r = 0; r < 4; ++r)
#pragma unroll
        for (int c = 0; c < 4; ++c) acc[r][c] = (f32x4){0.f, 0.f, 0.f, 0.f};

    STAGE_TILE(0);
    asm volatile("s_waitcnt vmcnt(0)" ::: "memory");
    __builtin_amdgcn_s_barrier();

    for (int t = 0; t < Dm / 64; ++t) {
        unsigned short* Ad = Alds[t & 1];
        unsigned short* Bd = Blds[t & 1];
        if (t + 1 < Dm / 64) STAGE_TILE(t + 1);

        bf16x8 a_[4][2], b_[4][2];

#define RD_A(fr, ks) \
    (*(const bf16x8*)&Ad[(wr + (fr) * 16 + l15) * 64 + ((((ks) * 4 + lg) ^ (l15 & 7)) * 8)])
#define RD_B(fc, ks) \
    (*(const bf16x8*)&Bd[(wc + (fc) * 16 + l15) * 64 + ((((ks) * 4 + lg) ^ (l15 & 7)) * 8)])

#pragma unroll
        for (int fr = 0; fr < 4; ++fr) {
            a_[fr][0] = RD_A(fr, 0); a_[fr][1] = RD_A(fr, 1);
        }
#pragma unroll
        for (int fc = 0; fc < 4; ++fc) {
            b_[fc][0] = RD_B(fc, 0); b_[fc][1] = RD_B(fc, 1);
        }
        __builtin_amdgcn_s_setprio(1);
#pragma unroll
        for (int fr = 0; fr < 4; ++fr)
#pragma unroll
            for (int fc = 0; fc < 4; ++fc)
#pragma unroll
                for (int ks = 0; ks < 2; ++ks)
                    acc[fr][fc] = __builtin_amdgcn_mfma_f32_16x16x32_bf16(
                        a_[fr][ks], b_[fc][ks], acc[fr][fc], 0, 0, 0);
        __builtin_amdgcn_s_setprio(0);

        asm volatile("s_waitcnt vmcnt(0)" ::: "memory");
        __builtin_amdgcn_s_barrier();        // single barrier per K-tile
#undef RD_A
#undef RD_B
    }

#pragma unroll
    for (int r = 0; r < 4; ++r) {
#pragma unroll
        for (int c = 0; c < 4; ++c) {
            const int mBase = m0 + wr + r * 16 + lg * 4;
            const int n = n0 + wc + c * 16 + l15;
            const float bv_ = bias[n];
#pragma unroll
            for (int rr = 0; rr < 4; ++rr)
                Cf[(size_t)(mBase + rr) * Dm + n] = acc[r][c][rr] + bv_;
        }
    }
#undef STAGE_TILE
}

// ---------------- flash attention: round-23 verified body ----
// 4 waves, QBLK=128, gload_lds staging, XCD-affine bid = qt*32 + (b*16+h).
__global__ __launch_bounds__(256) void attn_bf16(const unsigned short* q,
                                                 const unsigned short* __restrict__ k,
                                                 const unsigned short* __restrict__ vt,
                                                 unsigned short* ao) {
    __shared__ unsigned short KVs[2][2][64 * 64];  // [buf][0=K,1=Vt], XOR-swizzled
    const int bid = blockIdx.x;
    const int qt = bid >> 5;            // 0..15
    const int g  = bid & 31;            // b*16 + h
    const int b  = g >> 4, h = g & 15;
    const int tid = threadIdx.x, lane = tid & 63, wid = tid >> 6;
    const int l31 = lane & 31, hi = lane >> 5;

    const size_t qrow0 = (size_t)b * SQ + qt * 128;
    const unsigned short* qp = q + (qrow0 + wid * 32 + l31) * Dm + h * 64;
    bf16x8 qf[4];
#pragma unroll
    for (int ks = 0; ks < 4; ++ks)
        qf[ks] = *(const bf16x8*)&qp[ks * 16 + hi * 8];

    const unsigned short* kb = k + (size_t)b * SQ * Dm + h * 64;
    const unsigned short* vb = vt + ((size_t)b * NH + h) * 64 * SQ;

    const int wrow = wid * 8 + (lane >> 3);
    const int gcol = ((lane & 7) ^ ((lane >> 3) & 7)) * 8;

#define STAGE_KV(buf, T0)                                                          \
    do {                                                                           \
        unsigned short* Kd_ = &KVs[buf][0][0];                                     \
        unsigned short* Vd_ = &KVs[buf][1][0];                                     \
        _Pragma("unroll")                                                          \
        for (int i_ = 0; i_ < 2; ++i_) {                                           \
            gload_lds16(&kb[(size_t)((T0) + wrow + 32 * i_) * Dm + gcol],          \
                        &Kd_[i_ * 2048 + wid * 512]);                              \
            gload_lds16(&vb[(size_t)(wrow + 32 * i_) * SQ + (T0) + gcol],          \
                        &Vd_[i_ * 2048 + wid * 512]);                              \
        }                                                                          \
    } while (0)

    STAGE_KV(0, 0);
    asm volatile("s_waitcnt vmcnt(0)" ::: "memory");
    __builtin_amdgcn_s_barrier();

    float psum = 0.f;
    f32x16 c0, c1;
#pragma unroll
    for (int i = 0; i < 16; ++i) { c0[i] = 0.f; c1[i] = 0.f; }

    int cur = 0;
    for (int t0 = 0; t0 < SQ; t0 += 64) {
        if (t0 + 64 < SQ) STAGE_KV(cur ^ 1, t0 + 64);   // issue early; drains at tile end
        const unsigned short* Kc = KVs[cur][0];
        const unsigned short* Vc = KVs[cur][1];

#pragma unroll
        for (int kblk = 0; kblk < 2; ++kblk) {
            f32x16 p;
#pragma unroll
            for (int i = 0; i < 16; ++i) p[i] = 0.f;
            __builtin_amdgcn_s_setprio(1);
#pragma unroll
            for (int ks = 0; ks < 4; ++ks) {
                int row = kblk * 32 + l31;
                int slot = ((ks * 2 + hi) ^ (l31 & 7)) * 8;
                bf16x8 kf = *(const bf16x8*)&Kc[row * 64 + slot];
                p = __builtin_amdgcn_mfma_f32_32x32x16_bf16(kf, qf[ks], p, 0, 0, 0);
            }
            __builtin_amdgcn_s_setprio(0);

            float e[16];
#pragma unroll
            for (int i = 0; i < 16; ++i) { e[i] = exp2_fast(p[i]); psum += e[i]; }
            unsigned w0 = cvt_pk(e[0], e[1]),   w1 = cvt_pk(e[2], e[3]);
            unsigned w2 = cvt_pk(e[4], e[5]),   w3 = cvt_pk(e[6], e[7]);
            unsigned w4 = cvt_pk(e[8], e[9]),   w5 = cvt_pk(e[10], e[11]);
            unsigned w6 = cvt_pk(e[12], e[13]), w7 = cvt_pk(e[14], e[15]);
            permlane_swap(w0, w2); permlane_swap(w1, w3);
            permlane_swap(w4, w6); permlane_swap(w5, w7);
            bf16x8 pf0 = make_frag(w0, w1, w2, w3);
            bf16x8 pf1 = make_frag(w4, w5, w6, w7);

            int s0 = ((kblk * 4 + hi) ^ (l31 & 7)) * 8;
            int s1 = ((kblk * 4 + 2 + hi) ^ (l31 & 7)) * 8;
            bf16x8 va0 = *(const bf16x8*)&Vc[l31 * 64 + s0];
            bf16x8 va1 = *(const bf16x8*)&Vc[l31 * 64 + s1];
            bf16x8 vb0 = *(const bf16x8*)&Vc[(32 + l31) * 64 + s0];
            bf16x8 vb1 = *(const bf16x8*)&Vc[(32 + l31) * 64 + s1];
            __builtin_amdgcn_s_setprio(1);
            c0 = __builtin_amdgcn_mfma_f32_32x32x16_bf16(va0, pf0, c0, 0, 0, 0);
            c0 = __builtin_amdgcn_mfma_f32_32x32x16_bf16(va1, pf1, c0, 0, 0, 0);
            c1 = __builtin_amdgcn_mfma_f32_32x32x16_bf16(vb0, pf0, c1, 0, 0, 0);
            c1 = __builtin_amdgcn_mfma_f32_32x32x16_bf16(vb1, pf1, c1, 0, 0, 0);
            __builtin_amdgcn_s_setprio(0);
        }

        asm volatile("s_waitcnt vmcnt(0)" ::: "memory");
        __syncthreads();   // single barrier per tile
        cur ^= 1;
    }

    float s = psum + __shfl_xor(psum, 32, 64);
    float inv = 1.f / s;

    unsigned short* Olds = (unsigned short*)KVs;
    {
        const int orow = wid * 32 + l31;
#pragma unroll
        for (int db = 0; db < 2; ++db) {
#pragma unroll
            for (int i = 0; i < 8; ++i) {
                float lo  = (db ? c1[2 * i] : c0[2 * i]) * inv;
                float hi_ = (db ? c1[2 * i + 1] : c0[2 * i + 1]) * inv;
                unsigned w = cvt_pk(lo, hi_);
                int d7 = hi * 4 + (i & 1) * 2;
                int slot = db * 4 + (i >> 1);
                int sw = slot ^ (l31 & 7);
                *(unsigned*)&Olds[orow * 64 + sw * 8 + d7] = w;
            }
        }
    }
    __syncthreads();
    {
        int r = tid >> 1, half = tid & 1;
        unsigned short* dst = ao + (qrow0 + r) * Dm + h * 64 + half * 32;
#pragma unroll
        for (int j = 0; j < 4; ++j) {
            int slot = half * 4 + j;
            int sw = slot ^ (r & 7);
            *(uint4*)&dst[j * 8] = *(const uint4*)&Olds[r * 64 + sw * 8];
        }
    }
#undef STAGE_KV
}

extern "C" void kernel_launch(void* const* d_in, const int* in_sizes, int n_in,
                              void* d_out, int out_size, void* d_ws, size_t ws_size,
                              hipStream_t stream) {
    const float* x  = (const float*)d_in[0];
    const float* Wq = (const float*)d_in[1];
    const float* bq = (const float*)d_in[2];
    const float* Wk = (const float*)d_in[3];
    const float* bk = (const float*)d_in[4];
    const float* Wv = (const float*)d_in[5];
    const float* bv = (const float*)d_in[6];
    const float* Wo = (const float*)d_in[7];
    const float* bo = (const float*)d_in[8];
    float* out = (float*)d_out;

    const size_t M = (size_t)NB * SQ;           // 4096
    const size_t elems = M * Dm;                // 4M
    unsigned short* xb    = (unsigned short*)d_ws;
    unsigned short* wtb   = xb + elems;
    unsigned short* qbuf  = wtb + 4ull * Dm * Dm;
    unsigned short* kbuf  = qbuf + elems;
    unsigned short* vtbuf = kbuf + elems;

    dim3 blk(256);
    hipLaunchKernelGGL(prologue, dim3(16, 16, 5), blk, 0, stream,
                       x, Wq, Wk, Wv, Wo, xb, wtb);

    hipLaunchKernelGGL(gemm_qkv192, dim3(256), dim3(512), 0, stream,
                       xb, wtb, bq, bk, bv, qbuf, kbuf, vtbuf);

    hipLaunchKernelGGL(attn_bf16, dim3(512), blk, 0, stream,
                       qbuf, kbuf, vtbuf, qbuf);

    hipLaunchKernelGGL(gemm_out8, dim3(Dm / 128, M / 128), blk, 0, stream,
                       qbuf, wtb + 3ull * Dm * Dm, bo, out);
}